// Round 4
// baseline (124.719 us; speedup 1.0000x reference)
//
#include <hip/hip_runtime.h>
#include <hip/hip_fp16.h>

// SuppLayer: out[b,c] = exp( sum_s x[b, cm[c,s]] * w[c,s] )
// B=4096, NCLASS=1000, NSUPP=64, NCHUNK=4096.
//
// R13: VMEM-free gather phases with FULL support coverage.
//  R12 bug: supports were split across row-halves (each output row only
//  summed 32 of its 64 supports). Fix: each register-resident cm/w half
//  (8 int4 + 8 float4 = 64 VGPR) is applied to BOTH row-halves before
//  being swapped, so every row sees all 16 sg groups:
//    preload cw(0..7) -> stage lo -> bar -> issue hv loads ->
//    pass1 accl+=sg0..7@tlo (no VMEM; hv streams under it) ->
//    cvt hv->thi -> load cw(8..15) -> bar ->
//    pass2 accl+=sg8..15@tlo -> store lo ->
//    pass3 acch+=sg8..15@thi -> reload cw(0..7) ->
//    pass4 acch+=sg0..7@thi -> store hi.
//  vmcnt discipline: during pass1 the 32 hv x-loads are the ONLY
//  outstanding VMEM and nothing waits on them until the cvt phase
//  (single in-order vmcnt counter — any newer-load wait drains older).
//  Slot = 16 B = 8 rows fp16; read quad = idx&7; pre-pass counting-sorts
//  by (idx-c)&7 so a wave's 64 consecutive classes cycle all 8 quads.

constexpr int B_       = 4096;
constexpr int NCLASS_  = 1000;
constexpr int NSUPP_   = 64;
constexpr int NCHUNK_  = 4096;
constexpr int BT       = 16;     // batch rows per block
constexpr int BH       = BT / 2; // rows per half-tile
constexpr int THREADS_ = 1024;
constexpr int SG_      = NSUPP_ / 4;            // 16 int4/float4 groups
constexpr int SGH_     = SG_ / 2;               // 8 groups resident at a time
constexpr size_t CMT_BYTES = (size_t)SG_ * NCLASS_ * 16;   // 256 KB
constexpr size_t WS_NEEDED = 2 * CMT_BYTES;                // 512 KB

// ---- pre-pass: one wave per class. Sort 64 (idx,w) by key=(idx-c)&7 and
// write to [sg][class] transposed layout. All-register rank computation. ----
__global__ __launch_bounds__(256)
void build_cw_kernel(const int*   __restrict__ cm,
                     const float* __restrict__ w,
                     int*         __restrict__ cmT,
                     float*       __restrict__ wT)
{
    const int t    = threadIdx.x;
    const int c    = blockIdx.x * 4 + (t >> 6);   // 4 classes per block
    const int lane = t & 63;
    if (c >= NCLASS_) return;                      // grid=250 -> never taken

    const int   idx = cm[c * NSUPP_ + lane];
    const float wv  = w [c * NSUPP_ + lane];
    const int   key = (idx - c) & 7;               // read quad = idx&7

    // stable rank of this element in sorted-by-key order
    const unsigned long long below = ((unsigned long long)1 << lane) - 1ull;
    int j = 0;
    #pragma unroll
    for (int r = 0; r < 8; ++r) {
        const unsigned long long m = __ballot(key == r);
        if (key > r)  j += __popcll(m);
        if (key == r) j += __popcll(m & below);
    }

    const int dst = ((j >> 2) * NCLASS_ + c) * 4 + (j & 3);
    cmT[dst] = idx;
    wT [dst] = wv;
}

// gather 8 sg groups from one LDS half using register-resident cm/w: NO VMEM.
__device__ __forceinline__ void gather_half_reg(
    const float4* __restrict__ t4,
    const int4 cw[SGH_], const float4 wv[SGH_], float acc[BH])
{
    #pragma unroll
    for (int sg = 0; sg < SGH_; ++sg) {
        const int4   ci = cw[sg];
        const float4 wf = wv[sg];
        {
            const float4 d0 = t4[ci.x];
            const float4 d1 = t4[ci.y];
            const __half2* h0 = reinterpret_cast<const __half2*>(&d0);
            const __half2* h1 = reinterpret_cast<const __half2*>(&d1);
            #pragma unroll
            for (int k = 0; k < 4; ++k) {
                float2 f;
                f = __half22float2(h0[k]);
                acc[2 * k]     = fmaf(f.x, wf.x, acc[2 * k]);
                acc[2 * k + 1] = fmaf(f.y, wf.x, acc[2 * k + 1]);
                f = __half22float2(h1[k]);
                acc[2 * k]     = fmaf(f.x, wf.y, acc[2 * k]);
                acc[2 * k + 1] = fmaf(f.y, wf.y, acc[2 * k + 1]);
            }
        }
        {
            const float4 d2 = t4[ci.z];
            const float4 d3 = t4[ci.w];
            const __half2* h2 = reinterpret_cast<const __half2*>(&d2);
            const __half2* h3 = reinterpret_cast<const __half2*>(&d3);
            #pragma unroll
            for (int k = 0; k < 4; ++k) {
                float2 f;
                f = __half22float2(h2[k]);
                acc[2 * k]     = fmaf(f.x, wf.z, acc[2 * k]);
                acc[2 * k + 1] = fmaf(f.y, wf.z, acc[2 * k + 1]);
                f = __half22float2(h3[k]);
                acc[2 * k]     = fmaf(f.x, wf.w, acc[2 * k]);
                acc[2 * k + 1] = fmaf(f.y, wf.w, acc[2 * k + 1]);
            }
        }
    }
}

template <bool USET>
__device__ __forceinline__ void load_cw_half(
    const int4* __restrict__ cmT, const float4* __restrict__ wT,
    const int* __restrict__ cmap, const float* __restrict__ wSupp,
    const int c, const int h, int4 cw[SGH_], float4 wv[SGH_])
{
    #pragma unroll
    for (int sg = 0; sg < SGH_; ++sg) {
        if constexpr (USET) {
            cw[sg] = cmT[(h * SGH_ + sg) * NCLASS_ + c];
            wv[sg] = wT [(h * SGH_ + sg) * NCLASS_ + c];
        } else {
            cw[sg] = reinterpret_cast<const int4*>(cmap + c * NSUPP_)[h * SGH_ + sg];
            wv[sg] = reinterpret_cast<const float4*>(wSupp + c * NSUPP_)[h * SGH_ + sg];
        }
    }
}

template <bool USET>
__global__ __launch_bounds__(THREADS_, 4)
void supp_gather_kernel(const float* __restrict__ x,
                        const float* __restrict__ wSupp,
                        const int*   __restrict__ cmap,
                        const float4* __restrict__ wT,
                        const int4*   __restrict__ cmT,
                        float*       __restrict__ out)
{
    // two 64 KB halves; slot idx = 16 B = 8 rows as half2 pairs
    __shared__ __align__(16) __half2 tile[NCHUNK_ * 8];
    __half2* tlo = tile;
    __half2* thi = tile + NCHUNK_ * 4;

    const int t  = threadIdx.x;
    const int rb = blockIdx.x * BT;   // first batch row of this tile
    const int c  = t;                 // class (t < NCLASS_ only)

    // ---- preload cm/w for sg 0..7 (64 VGPR) ----
    int4   cw[SGH_];
    float4 wv[SGH_];
    if (t < NCLASS_)
        load_cw_half<USET>(cmT, wT, cmap, wSupp, c, 0, cw, wv);

    // ---- phase 1: stage rows rb..rb+7 -> fp16 -> tlo ----
    #pragma unroll
    for (int p = 0; p < NCHUNK_ / THREADS_; ++p) {
        const int col = t + THREADS_ * p;
        float v[BH];
        #pragma unroll
        for (int bi = 0; bi < BH; ++bi)
            v[bi] = x[(size_t)(rb + bi) * NCHUNK_ + col];
        __half2 h2v[BH / 2];
        #pragma unroll
        for (int k = 0; k < BH / 2; ++k)
            h2v[k] = __floats2half2_rn(v[2 * k], v[2 * k + 1]);
        *reinterpret_cast<float4*>(&tlo[(size_t)col * 4]) =
            *reinterpret_cast<const float4*>(&h2v[0]);
    }
    __syncthreads();

    // ---- phase 2: issue hi-row loads (only outstanding VMEM) ----
    float hv[4 * BH];
    #pragma unroll
    for (int p = 0; p < NCHUNK_ / THREADS_; ++p) {
        const int col = t + THREADS_ * p;
        #pragma unroll
        for (int bi = 0; bi < BH; ++bi)
            hv[p * BH + bi] = x[(size_t)(rb + BH + bi) * NCHUNK_ + col];
    }
    // pin: don't sink the loads into/past the gather
    __builtin_amdgcn_sched_barrier(0);

    // ---- pass 1: accl += sg0..7 @ tlo (pure LDS+VALU, no vmcnt waits) ----
    float accl[BH];
    if (t < NCLASS_) {
        #pragma unroll
        for (int bi = 0; bi < BH; ++bi) accl[bi] = 0.f;
        gather_half_reg(reinterpret_cast<const float4*>(tlo), cw, wv, accl);
    }

    // ---- cvt hv -> thi (vmcnt waits land here; hv streamed under pass 1) ----
    #pragma unroll
    for (int p = 0; p < NCHUNK_ / THREADS_; ++p) {
        const int col = t + THREADS_ * p;
        __half2 h2v[BH / 2];
        #pragma unroll
        for (int k = 0; k < BH / 2; ++k)
            h2v[k] = __floats2half2_rn(hv[p * BH + 2 * k], hv[p * BH + 2 * k + 1]);
        *reinterpret_cast<float4*>(&thi[(size_t)col * 4]) =
            *reinterpret_cast<const float4*>(&h2v[0]);
    }
    // swap in cm/w for sg 8..15 (L2-resident)
    if (t < NCLASS_)
        load_cw_half<USET>(cmT, wT, cmap, wSupp, c, 1, cw, wv);
    __syncthreads();

    if (t < NCLASS_) {
        // ---- pass 2: accl += sg8..15 @ tlo -> lo rows complete, store ----
        gather_half_reg(reinterpret_cast<const float4*>(tlo), cw, wv, accl);
        #pragma unroll
        for (int bi = 0; bi < BH; ++bi)
            out[(size_t)(rb + bi) * NCLASS_ + c] = __expf(accl[bi]);

        // ---- pass 3: acch += sg8..15 @ thi (reuses resident cm/w) ----
        float acch[BH];
        #pragma unroll
        for (int bi = 0; bi < BH; ++bi) acch[bi] = 0.f;
        gather_half_reg(reinterpret_cast<const float4*>(thi), cw, wv, acch);

        // ---- pass 4: reload sg0..7, acch += sg0..7 @ thi, store hi ----
        load_cw_half<USET>(cmT, wT, cmap, wSupp, c, 0, cw, wv);
        gather_half_reg(reinterpret_cast<const float4*>(thi), cw, wv, acch);
        #pragma unroll
        for (int bi = 0; bi < BH; ++bi)
            out[(size_t)(rb + BH + bi) * NCLASS_ + c] = __expf(acch[bi]);
    }
}

extern "C" void kernel_launch(void* const* d_in, const int* in_sizes, int n_in,
                              void* d_out, int out_size, void* d_ws, size_t ws_size,
                              hipStream_t stream) {
    const float* x  = (const float*)d_in[0];   // (B, NCHUNK) fp32
    const float* w  = (const float*)d_in[1];   // (NCLASS, NSUPP) fp32
    const int*   cm = (const int*)d_in[2];     // (NCLASS, NSUPP) int32
    float*       o  = (float*)d_out;           // (B, NCLASS) fp32

    int*   cmT = (int*)d_ws;
    float* wT  = (float*)((char*)d_ws + CMT_BYTES);

    const dim3 grid(B_ / BT);                  // 256 blocks, 1 per CU
    if (ws_size >= WS_NEEDED) {
        build_cw_kernel<<<dim3((NCLASS_ + 3) / 4), dim3(256), 0, stream>>>(
            cm, w, cmT, wT);
        supp_gather_kernel<true><<<grid, dim3(THREADS_), 0, stream>>>(
            x, w, cm, (const float4*)wT, (const int4*)cmT, o);
    } else {
        supp_gather_kernel<false><<<grid, dim3(THREADS_), 0, stream>>>(
            x, w, cm, (const float4*)wT, (const int4*)cmT, o);
    }
}